// Round 1
// baseline (9968.652 us; speedup 1.0000x reference)
//
#include <hip/hip_runtime.h>
#include <stdint.h>

#define S_LEN 512
#define NB    64
#define HID   256
#define G3    768
#define SB    32768   // S_LEN * NB
#define NLAYER 6

typedef short bf16x8 __attribute__((ext_vector_type(8)));
typedef float floatx4 __attribute__((ext_vector_type(4)));
typedef unsigned short u16;
typedef unsigned int   u32;

__device__ __forceinline__ float bf2f(u16 v) {
  u32 u = ((u32)v) << 16;
  return __builtin_bit_cast(float, u);
}
__device__ __forceinline__ u16 f2bf(float f) {
  u32 u = __builtin_bit_cast(u32, f);
  u = (u + 0x7FFFu + ((u >> 16) & 1u)) >> 16;
  return (u16)u;
}
__device__ __forceinline__ float fsigmoid(float x) {
  return __builtin_amdgcn_rcpf(1.0f + __expf(-x));
}
__device__ __forceinline__ float ftanh(float x) {
  return 1.0f - 2.0f * __builtin_amdgcn_rcpf(1.0f + __expf(x + x));
}

// ---------------------------------------------------------------------------
// detect_fp32: sample x as u16; count bf16 NaN/Inf exponent patterns.
// fp32 buffer -> low mantissa halves hit exp==0xFF ~0.39% (~500 in sample).
// genuine bf16 normals -> exactly 0. Flag = 1 means inputs are fp32.
// ---------------------------------------------------------------------------
__global__ void detect_fp32(const u16* __restrict__ x, int n, int* flag) {
  __shared__ int tot;
  if (threadIdx.x == 0) tot = 0;
  __syncthreads();
  int c = 0;
  for (int i = threadIdx.x; i < n; i += blockDim.x) {
    u16 v = x[i];
    if (((v >> 7) & 0xFF) == 0xFF) ++c;
  }
  atomicAdd(&tot, c);
  __syncthreads();
  if (threadIdx.x == 0) *flag = (tot > 64) ? 1 : 0;
}

// cvt: input (fp32 or bf16 per flag) -> packed bf16 copy in ws.
__global__ void cvt(const void* __restrict__ src, u16* __restrict__ dst,
                    int n, const int* __restrict__ flag) {
  const int stride = gridDim.x * blockDim.x;
  const bool isf32 = (*flag != 0);
  for (int i = blockIdx.x * blockDim.x + threadIdx.x; i < n; i += stride) {
    if (isf32) dst[i] = f2bf(((const float*)src)[i]);
    else       dst[i] = ((const u16*)src)[i];
  }
}

// write_out: fp32 staging -> d_out in the harness's output dtype per flag.
__global__ void write_out(const float* __restrict__ hNs, void* __restrict__ out,
                          int n, const int* __restrict__ flag) {
  int i = blockIdx.x * blockDim.x + threadIdx.x;
  if (i >= n) return;
  if (*flag) ((float*)out)[i] = hNs[i];
  else       ((u16*)out)[i]   = f2bf(hNs[i]);
}

// ---------------------------------------------------------------------------
// gate_gemm: out[dir][m][n] = sum_k A[m][k] * W[dir][n][k] + bias[dir][n]
// A: [SB][K] bf16 row-major. W: [2][768][K] bf16. out: [2][SB][768] bf16.
// 128x128 tile / WG, BK=64. Register-staged LDS, XOR-swizzled 16B chunks.
// ---------------------------------------------------------------------------
__global__ __launch_bounds__(256)
void gate_gemm(const u16* __restrict__ A, const u16* __restrict__ W,
               const u16* __restrict__ bias, u16* __restrict__ outg, int K) {
  const int m0  = blockIdx.x * 128;
  const int n0  = blockIdx.y * 128;
  const int dir = blockIdx.z;
  W    += (size_t)dir * G3 * K;
  bias += (size_t)dir * G3;
  outg += (size_t)dir * (size_t)SB * G3;

  __shared__ __align__(16) u16 lA[8192];   // 128 rows x 64 k, chunk-swizzled
  __shared__ __align__(16) u16 lB[8192];

  const int tid  = threadIdx.x;
  const int lane = tid & 63;
  const int wv   = tid >> 6;
  const int wm   = wv & 1, wn = wv >> 1;
  const int l15  = lane & 15, quad = lane >> 4;

  floatx4 acc[4][4] = {};   // [mt][nt]

  for (int k0 = 0; k0 < K; k0 += 64) {
    bf16x8 ra[4], rb[4];
#pragma unroll
    for (int i = 0; i < 4; ++i) {
      int c   = i * 256 + tid;          // chunk 0..1023
      int row = c >> 3;
      int kc  = (c & 7) ^ (row & 7);    // XOR-swizzled source chunk
      ra[i] = *(const bf16x8*)(A + (size_t)(m0 + row) * K + (k0 + kc * 8));
      rb[i] = *(const bf16x8*)(W + (size_t)(n0 + row) * K + (k0 + kc * 8));
    }
    __syncthreads();   // previous tile's LDS reads complete
#pragma unroll
    for (int i = 0; i < 4; ++i) {
      *(bf16x8*)(lA + (size_t)(i * 256 + tid) * 8) = ra[i];
      *(bf16x8*)(lB + (size_t)(i * 256 + tid) * 8) = rb[i];
    }
    __syncthreads();

#pragma unroll
    for (int kt = 0; kt < 2; ++kt) {
      bf16x8 af[4], bfr[4];
#pragma unroll
      for (int mt = 0; mt < 4; ++mt) {
        int row = wm * 64 + mt * 16 + l15;
        int ch  = row * 8 + ((kt * 4 + quad) ^ (row & 7));
        af[mt] = *(const bf16x8*)(lA + ch * 8);
      }
#pragma unroll
      for (int nt = 0; nt < 4; ++nt) {
        int row = wn * 64 + nt * 16 + l15;
        int ch  = row * 8 + ((kt * 4 + quad) ^ (row & 7));
        bfr[nt] = *(const bf16x8*)(lB + ch * 8);
      }
#pragma unroll
      for (int mt = 0; mt < 4; ++mt)
#pragma unroll
        for (int nt = 0; nt < 4; ++nt)
          acc[mt][nt] = __builtin_amdgcn_mfma_f32_16x16x32_bf16(
              af[mt], bfr[nt], acc[mt][nt], 0, 0, 0);
    }
  }
  __syncthreads();

  // epilogue: C/D layout col(n)=lane&15, row(m)=quad*4+reg
#pragma unroll
  for (int nt = 0; nt < 4; ++nt) {
    int n    = n0 + wn * 64 + nt * 16 + l15;
    float bv = bf2f(bias[n]);
#pragma unroll
    for (int mt = 0; mt < 4; ++mt) {
#pragma unroll
      for (int r = 0; r < 4; ++r) {
        int m = m0 + wm * 64 + mt * 16 + quad * 4 + r;
        outg[(size_t)m * G3 + n] = f2bf(acc[mt][nt][r] + bv);
      }
    }
  }
}

// ---------------------------------------------------------------------------
// gru_scan v2: sequential recurrence, one barrier per step, gates stay in
// accumulator registers.
// grid = 8 WGs: blockIdx.x = dir + 2*batch_group (4 groups of 16 batch rows).
// 512 threads = 8 waves. Wave wv owns hidden units j in [wv*32, wv*32+32):
// it computes gate rows n = {j, 256+j, 512+j} so the r/z/n preacts for a
// given (batch,j) land in the SAME lane (C/D layout: col=lane&15=j-within-16,
// row=quad*4+reg=batch). Gate math runs directly on acc; h is double-buffered
// in LDS (one barrier/step); x-gates prefetched a full step ahead in the
// fragment layout (x_r/x_z folded into acc init; x_n kept separate since the
// reset gate scales only the h-part of the n-gate).
// ---------------------------------------------------------------------------
__global__ __launch_bounds__(512, 2)
void gru_scan(const u16* __restrict__ gateX,   // [2][SB][768] bf16
              const u16* __restrict__ Whh,     // [2][768][256] (this layer)
              const u16* __restrict__ Bhh,     // [2][768]
              const u16* __restrict__ H0,      // [12][64][256] bf16 copy
              u16* __restrict__ layerOut,      // [SB][512] bf16
              float* __restrict__ hNs,         // fp32 staging [12][64][256]
              int layer) {
  const int dir = blockIdx.x & 1;
  const int bg  = blockIdx.x >> 1;
  const int tid = threadIdx.x;
  const int lane = tid & 63;
  const int wv   = tid >> 6;           // 0..7: owns hidden units [wv*32, wv*32+32)
  const int l15  = lane & 15, quad = lane >> 4;

  __shared__ __align__(16) u16 hbuf[2][16][264];  // double-buffered h, +8 pad

  // stationary W_hh fragments: n = g*256 + wv*32 + nt*16 + l15, k = kt*32+quad*8
  const u16* Wd = Whh + (size_t)dir * G3 * HID;
  bf16x8 wfr[8][3][2];                 // [kt][gate][j-tile]
  float  bh[3][2];
#pragma unroll
  for (int g = 0; g < 3; ++g)
#pragma unroll
    for (int nt = 0; nt < 2; ++nt) {
      int n = g * 256 + wv * 32 + nt * 16 + l15;
      bh[g][nt] = bf2f(Bhh[dir * G3 + n]);
#pragma unroll
      for (int kt = 0; kt < 8; ++kt)
        wfr[kt][g][nt] = *(const bf16x8*)(Wd + (size_t)n * HID + kt * 32 + quad * 8);
    }

  const int jbase = wv * 32;           // + nt*16 + l15 -> hidden unit
  const int mrow  = quad * 4;          // first of this lane's 4 batch rows
  const int b0    = bg * 16 + mrow;    // global batch row at r=0

  // init hbuf[0] cooperatively: 16 rows x 256 cols = 512 bf16x8 chunks
  {
    int row = tid >> 5, col = (tid & 31) * 8;
    const u16* hp = H0 + ((size_t)(layer * 2 + dir) * NB + bg * 16 + row) * HID + col;
    *(bf16x8*)(&hbuf[0][row][col]) = *(const bf16x8*)hp;
  }
  // per-lane previous-h registers (match hbuf content exactly)
  float hreg[2][4];
#pragma unroll
  for (int nt = 0; nt < 2; ++nt)
#pragma unroll
    for (int r = 0; r < 4; ++r)
      hreg[nt][r] = bf2f(H0[((size_t)(layer * 2 + dir) * NB + b0 + r) * HID +
                            jbase + nt * 16 + l15]);

  const size_t dbase = (size_t)dir * SB * G3;
  const u16* xbase = gateX + dbase + (size_t)b0 * G3 + jbase + l15;

  // prefetch x-gates for step 0 (fragment layout: one u16 per (gate,jtile,row))
  u16 xpre[3][2][4];
  {
    const int s0 = dir ? (S_LEN - 1) : 0;
    const u16* xp = xbase + (size_t)s0 * NB * G3;
#pragma unroll
    for (int g = 0; g < 3; ++g)
#pragma unroll
      for (int nt = 0; nt < 2; ++nt)
#pragma unroll
        for (int r = 0; r < 4; ++r)
          xpre[g][nt][r] = xp[(size_t)r * G3 + g * 256 + nt * 16];
  }
  __syncthreads();

  for (int t = 0; t < S_LEN; ++t) {
    const int s   = dir ? (S_LEN - 1 - t) : t;
    const int cur = t & 1, nxt = cur ^ 1;

    // consume xpre: acc init = b_hh + x for r/z gates; x_n kept separate
    floatx4 acc[3][2];
    float xn_f[2][4];
#pragma unroll
    for (int nt = 0; nt < 2; ++nt)
#pragma unroll
      for (int r = 0; r < 4; ++r) {
        acc[0][nt][r] = bh[0][nt] + bf2f(xpre[0][nt][r]);
        acc[1][nt][r] = bh[1][nt] + bf2f(xpre[1][nt][r]);
        xn_f[nt][r]   = bf2f(xpre[2][nt][r]);
        acc[2][nt][r] = bh[2][nt];
      }

    // issue next step's x prefetch (covered by ~1 full step of MFMA+gates)
    {
      const int tn = (t < S_LEN - 1) ? t + 1 : t;
      const int sn = dir ? (S_LEN - 1 - tn) : tn;
      const u16* xp = xbase + (size_t)sn * NB * G3;
#pragma unroll
      for (int g = 0; g < 3; ++g)
#pragma unroll
        for (int nt = 0; nt < 2; ++nt)
#pragma unroll
          for (int r = 0; r < 4; ++r)
            xpre[g][nt][r] = xp[(size_t)r * G3 + g * 256 + nt * 16];
    }

    // MFMA phase: acc += h @ Whh^T   (A-frag identical for all waves)
#pragma unroll
    for (int kt = 0; kt < 8; ++kt) {
      bf16x8 af = *(const bf16x8*)(&hbuf[cur][l15][kt * 32 + quad * 8]);
#pragma unroll
      for (int g = 0; g < 3; ++g)
#pragma unroll
        for (int nt = 0; nt < 2; ++nt)
          acc[g][nt] = __builtin_amdgcn_mfma_f32_16x16x32_bf16(
              af, wfr[kt][g][nt], acc[g][nt], 0, 0, 0);
    }

    // gate phase: directly on accumulator fragments, no LDS round trip
#pragma unroll
    for (int nt = 0; nt < 2; ++nt)
#pragma unroll
      for (int r = 0; r < 4; ++r) {
        float rg = fsigmoid(acc[0][nt][r]);
        float zg = fsigmoid(acc[1][nt][r]);
        float ng = ftanh(xn_f[nt][r] + rg * acc[2][nt][r]);
        float hn = ng + zg * (hreg[nt][r] - ng);
        hreg[nt][r] = hn;
        u16 hb = f2bf(hn);
        hbuf[nxt][mrow + r][jbase + nt * 16 + l15] = hb;
        layerOut[((size_t)s * NB + b0 + r) * 512 + dir * HID +
                 jbase + nt * 16 + l15] = hb;
      }

    if (t == S_LEN - 1) {
#pragma unroll
      for (int nt = 0; nt < 2; ++nt)
#pragma unroll
        for (int r = 0; r < 4; ++r)
          hNs[((size_t)(layer * 2 + dir) * NB + b0 + r) * HID +
              jbase + nt * 16 + l15] = hreg[nt][r];
    }
    __syncthreads();   // single barrier: h[nxt] complete before next MFMA
  }
}

// ---------------------------------------------------------------------------
extern "C" void kernel_launch(void* const* d_in, const int* in_sizes, int n_in,
                              void* d_out, int out_size, void* d_ws, size_t ws_size,
                              hipStream_t stream) {
  (void)n_in; (void)ws_size;
  char* ws = (char*)d_ws;
  // ws layout (176 MiB total):
  //   [0, 4K)        flag
  //   [4K, 1M)       hNs fp32 staging (786432 B)
  //   [1M, 16M)      bf16 copies: h0, wih0, wih, whh, bih, bhh (~12.8 MiB)
  //   [16M, 112M)    gateX bf16 [2][SB][768]
  //   [112M, 144M)   bufA bf16 [SB][512]
  //   [144M, 176M)   bufB bf16 [SB][512]  (xC aliases: consumed layer 0 only)
  int*   flag  = (int*)ws;
  float* hNs   = (float*)(ws + 4096);
  u16*   h0C   = (u16*)(ws + (1u << 20));
  u16*   wih0C = h0C   + 196608;
  u16*   wihC  = wih0C + 196608;
  u16*   whhC  = wihC  + 3932160;
  u16*   bihC  = whhC  + 2359296;
  u16*   bhhC  = bihC  + 9216;
  u16*   gateX = (u16*)(ws + (16u  << 20));
  u16*   bufA  = (u16*)(ws + (112u << 20));
  u16*   bufB  = (u16*)(ws + (144u << 20));
  u16*   xC    = bufB;   // aliased; layer-0 gemm reads it before bufB written

  detect_fp32<<<1, 1024, 0, stream>>>((const u16*)d_in[0], 262144, flag);
  cvt<<<512, 256, 0, stream>>>(d_in[0], xC,    in_sizes[0], flag);
  cvt<<<256, 256, 0, stream>>>(d_in[1], h0C,   in_sizes[1], flag);
  cvt<<<256, 256, 0, stream>>>(d_in[2], wih0C, in_sizes[2], flag);
  cvt<<<512, 256, 0, stream>>>(d_in[3], wihC,  in_sizes[3], flag);
  cvt<<<512, 256, 0, stream>>>(d_in[4], whhC,  in_sizes[4], flag);
  cvt<<< 64, 256, 0, stream>>>(d_in[5], bihC,  in_sizes[5], flag);
  cvt<<< 64, 256, 0, stream>>>(d_in[6], bhhC,  in_sizes[6], flag);

  for (int layer = 0; layer < NLAYER; ++layer) {
    const u16* inp = (layer == 0) ? xC : ((layer & 1) ? bufA : bufB);
    u16* outBuf    = (layer & 1) ? bufB : bufA;

    const int K = (layer == 0) ? 128 : 512;
    const u16* W = (layer == 0) ? wih0C
                                : (wihC + (size_t)(layer - 1) * 2 * G3 * 512);
    dim3 grid(256, 6, 2);
    gate_gemm<<<grid, 256, 0, stream>>>(inp, W, bihC + (size_t)layer * 2 * G3,
                                        gateX, K);
    gru_scan<<<8, 512, 0, stream>>>(gateX, whhC + (size_t)layer * 2 * G3 * HID,
                                    bhhC + (size_t)layer * 2 * G3, h0C,
                                    outBuf, hNs, layer);
  }
  write_out<<<(out_size + 255) / 256, 256, 0, stream>>>(hNs, d_out, out_size, flag);
}

// Round 2
// 9577.072 us; speedup vs baseline: 1.0409x; 1.0409x over previous
//
#include <hip/hip_runtime.h>
#include <stdint.h>

#define S_LEN 512
#define NB    64
#define HID   256
#define G3    768
#define SB    32768   // S_LEN * NB
#define NLAYER 6

typedef short bf16x8 __attribute__((ext_vector_type(8)));
typedef float floatx4 __attribute__((ext_vector_type(4)));
typedef unsigned short u16;
typedef unsigned int   u32;

__device__ __forceinline__ float bf2f(u16 v) {
  u32 u = ((u32)v) << 16;
  return __builtin_bit_cast(float, u);
}
__device__ __forceinline__ u16 f2bf(float f) {
  u32 u = __builtin_bit_cast(u32, f);
  u = (u + 0x7FFFu + ((u >> 16) & 1u)) >> 16;
  return (u16)u;
}
__device__ __forceinline__ float fsigmoid(float x) {
  return __builtin_amdgcn_rcpf(1.0f + __expf(-x));
}
__device__ __forceinline__ float ftanh(float x) {
  return 1.0f - 2.0f * __builtin_amdgcn_rcpf(1.0f + __expf(x + x));
}

// LDS-only barrier: order hbuf writes across waves WITHOUT draining vmcnt.
// __syncthreads() emits s_waitcnt vmcnt(0) which would stall on the gateX
// prefetch loads and layerOut stores every step (the v2 regression).
__device__ __forceinline__ void lds_barrier() {
  asm volatile("s_waitcnt lgkmcnt(0)\n\ts_barrier" ::: "memory");
}

// ---------------------------------------------------------------------------
// detect_fp32: sample x as u16; count bf16 NaN/Inf exponent patterns.
// fp32 buffer -> low mantissa halves hit exp==0xFF ~0.39% (~500 in sample).
// genuine bf16 normals -> exactly 0. Flag = 1 means inputs are fp32.
// ---------------------------------------------------------------------------
__global__ void detect_fp32(const u16* __restrict__ x, int n, int* flag) {
  __shared__ int tot;
  if (threadIdx.x == 0) tot = 0;
  __syncthreads();
  int c = 0;
  for (int i = threadIdx.x; i < n; i += blockDim.x) {
    u16 v = x[i];
    if (((v >> 7) & 0xFF) == 0xFF) ++c;
  }
  atomicAdd(&tot, c);
  __syncthreads();
  if (threadIdx.x == 0) *flag = (tot > 64) ? 1 : 0;
}

// cvt: input (fp32 or bf16 per flag) -> packed bf16 copy in ws.
__global__ void cvt(const void* __restrict__ src, u16* __restrict__ dst,
                    int n, const int* __restrict__ flag) {
  const int stride = gridDim.x * blockDim.x;
  const bool isf32 = (*flag != 0);
  for (int i = blockIdx.x * blockDim.x + threadIdx.x; i < n; i += stride) {
    if (isf32) dst[i] = f2bf(((const float*)src)[i]);
    else       dst[i] = ((const u16*)src)[i];
  }
}

// write_out: fp32 staging -> d_out in the harness's output dtype per flag.
__global__ void write_out(const float* __restrict__ hNs, void* __restrict__ out,
                          int n, const int* __restrict__ flag) {
  int i = blockIdx.x * blockDim.x + threadIdx.x;
  if (i >= n) return;
  if (*flag) ((float*)out)[i] = hNs[i];
  else       ((u16*)out)[i]   = f2bf(hNs[i]);
}

// ---------------------------------------------------------------------------
// gate_gemm: out[dir][m][n] = sum_k A[m][k] * W[dir][n][k] + bias[dir][n]
// A: [SB][K] bf16 row-major. W: [2][768][K] bf16. out: [2][SB][768] bf16.
// 128x128 tile / WG, BK=64. Register-staged LDS, XOR-swizzled 16B chunks.
// ---------------------------------------------------------------------------
__global__ __launch_bounds__(256)
void gate_gemm(const u16* __restrict__ A, const u16* __restrict__ W,
               const u16* __restrict__ bias, u16* __restrict__ outg, int K) {
  const int m0  = blockIdx.x * 128;
  const int n0  = blockIdx.y * 128;
  const int dir = blockIdx.z;
  W    += (size_t)dir * G3 * K;
  bias += (size_t)dir * G3;
  outg += (size_t)dir * (size_t)SB * G3;

  __shared__ __align__(16) u16 lA[8192];   // 128 rows x 64 k, chunk-swizzled
  __shared__ __align__(16) u16 lB[8192];

  const int tid  = threadIdx.x;
  const int lane = tid & 63;
  const int wv   = tid >> 6;
  const int wm   = wv & 1, wn = wv >> 1;
  const int l15  = lane & 15, quad = lane >> 4;

  floatx4 acc[4][4] = {};   // [mt][nt]

  for (int k0 = 0; k0 < K; k0 += 64) {
    bf16x8 ra[4], rb[4];
#pragma unroll
    for (int i = 0; i < 4; ++i) {
      int c   = i * 256 + tid;          // chunk 0..1023
      int row = c >> 3;
      int kc  = (c & 7) ^ (row & 7);    // XOR-swizzled source chunk
      ra[i] = *(const bf16x8*)(A + (size_t)(m0 + row) * K + (k0 + kc * 8));
      rb[i] = *(const bf16x8*)(W + (size_t)(n0 + row) * K + (k0 + kc * 8));
    }
    __syncthreads();   // previous tile's LDS reads complete
#pragma unroll
    for (int i = 0; i < 4; ++i) {
      *(bf16x8*)(lA + (size_t)(i * 256 + tid) * 8) = ra[i];
      *(bf16x8*)(lB + (size_t)(i * 256 + tid) * 8) = rb[i];
    }
    __syncthreads();

#pragma unroll
    for (int kt = 0; kt < 2; ++kt) {
      bf16x8 af[4], bfr[4];
#pragma unroll
      for (int mt = 0; mt < 4; ++mt) {
        int row = wm * 64 + mt * 16 + l15;
        int ch  = row * 8 + ((kt * 4 + quad) ^ (row & 7));
        af[mt] = *(const bf16x8*)(lA + ch * 8);
      }
#pragma unroll
      for (int nt = 0; nt < 4; ++nt) {
        int row = wn * 64 + nt * 16 + l15;
        int ch  = row * 8 + ((kt * 4 + quad) ^ (row & 7));
        bfr[nt] = *(const bf16x8*)(lB + ch * 8);
      }
#pragma unroll
      for (int mt = 0; mt < 4; ++mt)
#pragma unroll
        for (int nt = 0; nt < 4; ++nt)
          acc[mt][nt] = __builtin_amdgcn_mfma_f32_16x16x32_bf16(
              af[mt], bfr[nt], acc[mt][nt], 0, 0, 0);
    }
  }
  __syncthreads();

  // epilogue: C/D layout col(n)=lane&15, row(m)=quad*4+reg
#pragma unroll
  for (int nt = 0; nt < 4; ++nt) {
    int n    = n0 + wn * 64 + nt * 16 + l15;
    float bv = bf2f(bias[n]);
#pragma unroll
    for (int mt = 0; mt < 4; ++mt) {
#pragma unroll
      for (int r = 0; r < 4; ++r) {
        int m = m0 + wm * 64 + mt * 16 + quad * 4 + r;
        outg[(size_t)m * G3 + n] = f2bf(acc[mt][nt][r] + bv);
      }
    }
  }
}

// ---------------------------------------------------------------------------
// gru_scan v3: v2 dataflow (gates resident in accumulators, one barrier per
// step, double-buffered h in LDS) + LDS-only barrier so the per-step
// __syncthreads no longer drains vmcnt(0). The gateX prefetch loads (issued a
// full step ahead) and the layerOut stores now stay in flight across the
// barrier; only DS ordering is enforced per step.
// grid = 8 WGs: blockIdx.x = dir + 2*batch_group. 512 threads = 8 waves.
// Wave wv owns hidden units [wv*32, wv*32+32): gate rows n = {j,256+j,512+j},
// so r/z/n preacts for a given (batch,j) land in the same lane.
// ---------------------------------------------------------------------------
__global__ __launch_bounds__(512, 2)
void gru_scan(const u16* __restrict__ gateX,   // [2][SB][768] bf16
              const u16* __restrict__ Whh,     // [2][768][256] (this layer)
              const u16* __restrict__ Bhh,     // [2][768]
              const u16* __restrict__ H0,      // [12][64][256] bf16 copy
              u16* __restrict__ layerOut,      // [SB][512] bf16
              float* __restrict__ hNs,         // fp32 staging [12][64][256]
              int layer) {
  const int dir = blockIdx.x & 1;
  const int bg  = blockIdx.x >> 1;
  const int tid = threadIdx.x;
  const int lane = tid & 63;
  const int wv   = tid >> 6;           // 0..7: owns hidden units [wv*32, wv*32+32)
  const int l15  = lane & 15, quad = lane >> 4;

  __shared__ __align__(16) u16 hbuf[2][16][264];  // double-buffered h, +8 pad

  // stationary W_hh fragments: n = g*256 + wv*32 + nt*16 + l15, k = kt*32+quad*8
  const u16* Wd = Whh + (size_t)dir * G3 * HID;
  bf16x8 wfr[8][3][2];                 // [kt][gate][j-tile]
  float  bh[3][2];
#pragma unroll
  for (int g = 0; g < 3; ++g)
#pragma unroll
    for (int nt = 0; nt < 2; ++nt) {
      int n = g * 256 + wv * 32 + nt * 16 + l15;
      bh[g][nt] = bf2f(Bhh[dir * G3 + n]);
#pragma unroll
      for (int kt = 0; kt < 8; ++kt)
        wfr[kt][g][nt] = *(const bf16x8*)(Wd + (size_t)n * HID + kt * 32 + quad * 8);
    }

  const int jbase = wv * 32;           // + nt*16 + l15 -> hidden unit
  const int mrow  = quad * 4;          // first of this lane's 4 batch rows
  const int b0    = bg * 16 + mrow;    // global batch row at r=0

  // init hbuf[0] cooperatively: 16 rows x 256 cols = 512 bf16x8 chunks
  {
    int row = tid >> 5, col = (tid & 31) * 8;
    const u16* hp = H0 + ((size_t)(layer * 2 + dir) * NB + bg * 16 + row) * HID + col;
    *(bf16x8*)(&hbuf[0][row][col]) = *(const bf16x8*)hp;
  }
  // per-lane previous-h registers (match hbuf content exactly)
  float hreg[2][4];
#pragma unroll
  for (int nt = 0; nt < 2; ++nt)
#pragma unroll
    for (int r = 0; r < 4; ++r)
      hreg[nt][r] = bf2f(H0[((size_t)(layer * 2 + dir) * NB + b0 + r) * HID +
                            jbase + nt * 16 + l15]);

  const size_t dbase = (size_t)dir * SB * G3;
  const u16* xbase = gateX + dbase + (size_t)b0 * G3 + jbase + l15;

  // prefetch x-gates for step 0 (fragment layout: one u16 per (gate,jtile,row))
  u16 xpre[3][2][4];
  {
    const int s0 = dir ? (S_LEN - 1) : 0;
    const u16* xp = xbase + (size_t)s0 * NB * G3;
#pragma unroll
    for (int g = 0; g < 3; ++g)
#pragma unroll
      for (int nt = 0; nt < 2; ++nt)
#pragma unroll
        for (int r = 0; r < 4; ++r)
          xpre[g][nt][r] = xp[(size_t)r * G3 + g * 256 + nt * 16];
  }
  lds_barrier();

  for (int t = 0; t < S_LEN; ++t) {
    const int s   = dir ? (S_LEN - 1 - t) : t;
    const int cur = t & 1, nxt = cur ^ 1;

    // consume xpre: acc init = b_hh + x for r/z gates; x_n kept separate
    floatx4 acc[3][2];
    float xn_f[2][4];
#pragma unroll
    for (int nt = 0; nt < 2; ++nt)
#pragma unroll
      for (int r = 0; r < 4; ++r) {
        acc[0][nt][r] = bh[0][nt] + bf2f(xpre[0][nt][r]);
        acc[1][nt][r] = bh[1][nt] + bf2f(xpre[1][nt][r]);
        xn_f[nt][r]   = bf2f(xpre[2][nt][r]);
        acc[2][nt][r] = bh[2][nt];
      }

    // issue next step's x prefetch; stays in flight across the lds_barrier
    {
      const int tn = (t < S_LEN - 1) ? t + 1 : t;
      const int sn = dir ? (S_LEN - 1 - tn) : tn;
      const u16* xp = xbase + (size_t)sn * NB * G3;
#pragma unroll
      for (int g = 0; g < 3; ++g)
#pragma unroll
        for (int nt = 0; nt < 2; ++nt)
#pragma unroll
          for (int r = 0; r < 4; ++r)
            xpre[g][nt][r] = xp[(size_t)r * G3 + g * 256 + nt * 16];
    }

    // MFMA phase: acc += h @ Whh^T   (A-frag identical for all waves)
#pragma unroll
    for (int kt = 0; kt < 8; ++kt) {
      bf16x8 af = *(const bf16x8*)(&hbuf[cur][l15][kt * 32 + quad * 8]);
#pragma unroll
      for (int g = 0; g < 3; ++g)
#pragma unroll
        for (int nt = 0; nt < 2; ++nt)
          acc[g][nt] = __builtin_amdgcn_mfma_f32_16x16x32_bf16(
              af, wfr[kt][g][nt], acc[g][nt], 0, 0, 0);
    }

    // gate phase: directly on accumulator fragments, no LDS round trip
#pragma unroll
    for (int nt = 0; nt < 2; ++nt)
#pragma unroll
      for (int r = 0; r < 4; ++r) {
        float rg = fsigmoid(acc[0][nt][r]);
        float zg = fsigmoid(acc[1][nt][r]);
        float ng = ftanh(xn_f[nt][r] + rg * acc[2][nt][r]);
        float hn = ng + zg * (hreg[nt][r] - ng);
        hreg[nt][r] = hn;
        u16 hb = f2bf(hn);
        hbuf[nxt][mrow + r][jbase + nt * 16 + l15] = hb;
        layerOut[((size_t)s * NB + b0 + r) * 512 + dir * HID +
                 jbase + nt * 16 + l15] = hb;   // fire-and-forget
      }

    lds_barrier();   // h[nxt] visible; vmcnt traffic stays in flight
  }

  // epilogue: final hidden state (fp32 staging)
#pragma unroll
  for (int nt = 0; nt < 2; ++nt)
#pragma unroll
    for (int r = 0; r < 4; ++r)
      hNs[((size_t)(layer * 2 + dir) * NB + b0 + r) * HID +
          jbase + nt * 16 + l15] = hreg[nt][r];
}

// ---------------------------------------------------------------------------
extern "C" void kernel_launch(void* const* d_in, const int* in_sizes, int n_in,
                              void* d_out, int out_size, void* d_ws, size_t ws_size,
                              hipStream_t stream) {
  (void)n_in; (void)ws_size;
  char* ws = (char*)d_ws;
  // ws layout (176 MiB total):
  //   [0, 4K)        flag
  //   [4K, 1M)       hNs fp32 staging (786432 B)
  //   [1M, 16M)      bf16 copies: h0, wih0, wih, whh, bih, bhh (~12.8 MiB)
  //   [16M, 112M)    gateX bf16 [2][SB][768]
  //   [112M, 144M)   bufA bf16 [SB][512]
  //   [144M, 176M)   bufB bf16 [SB][512]  (xC aliases: consumed layer 0 only)
  int*   flag  = (int*)ws;
  float* hNs   = (float*)(ws + 4096);
  u16*   h0C   = (u16*)(ws + (1u << 20));
  u16*   wih0C = h0C   + 196608;
  u16*   wihC  = wih0C + 196608;
  u16*   whhC  = wihC  + 3932160;
  u16*   bihC  = whhC  + 2359296;
  u16*   bhhC  = bihC  + 9216;
  u16*   gateX = (u16*)(ws + (16u  << 20));
  u16*   bufA  = (u16*)(ws + (112u << 20));
  u16*   bufB  = (u16*)(ws + (144u << 20));
  u16*   xC    = bufB;   // aliased; layer-0 gemm reads it before bufB written

  detect_fp32<<<1, 1024, 0, stream>>>((const u16*)d_in[0], 262144, flag);
  cvt<<<512, 256, 0, stream>>>(d_in[0], xC,    in_sizes[0], flag);
  cvt<<<256, 256, 0, stream>>>(d_in[1], h0C,   in_sizes[1], flag);
  cvt<<<256, 256, 0, stream>>>(d_in[2], wih0C, in_sizes[2], flag);
  cvt<<<512, 256, 0, stream>>>(d_in[3], wihC,  in_sizes[3], flag);
  cvt<<<512, 256, 0, stream>>>(d_in[4], whhC,  in_sizes[4], flag);
  cvt<<< 64, 256, 0, stream>>>(d_in[5], bihC,  in_sizes[5], flag);
  cvt<<< 64, 256, 0, stream>>>(d_in[6], bhhC,  in_sizes[6], flag);

  for (int layer = 0; layer < NLAYER; ++layer) {
    const u16* inp = (layer == 0) ? xC : ((layer & 1) ? bufA : bufB);
    u16* outBuf    = (layer & 1) ? bufB : bufA;

    const int K = (layer == 0) ? 128 : 512;
    const u16* W = (layer == 0) ? wih0C
                                : (wihC + (size_t)(layer - 1) * 2 * G3 * 512);
    dim3 grid(256, 6, 2);
    gate_gemm<<<grid, 256, 0, stream>>>(inp, W, bihC + (size_t)layer * 2 * G3,
                                        gateX, K);
    gru_scan<<<8, 512, 0, stream>>>(gateX, whhC + (size_t)layer * 2 * G3 * HID,
                                    bhhC + (size_t)layer * 2 * G3, h0C,
                                    outBuf, hNs, layer);
  }
  write_out<<<(out_size + 255) / 256, 256, 0, stream>>>(hNs, d_out, out_size, flag);
}

// Round 3
// 9073.154 us; speedup vs baseline: 1.0987x; 1.0555x over previous
//
#include <hip/hip_runtime.h>
#include <stdint.h>

#define S_LEN 512
#define NB    64
#define HID   256
#define G3    768
#define SB    32768   // S_LEN * NB
#define NLAYER 6

typedef short bf16x8 __attribute__((ext_vector_type(8)));
typedef short bf16x4 __attribute__((ext_vector_type(4)));
typedef float floatx4 __attribute__((ext_vector_type(4)));
typedef unsigned short u16;
typedef unsigned int   u32;

__device__ __forceinline__ float bf2f(u16 v) {
  u32 u = ((u32)v) << 16;
  return __builtin_bit_cast(float, u);
}
__device__ __forceinline__ u16 f2bf(float f) {
  u32 u = __builtin_bit_cast(u32, f);
  u = (u + 0x7FFFu + ((u >> 16) & 1u)) >> 16;
  return (u16)u;
}
__device__ __forceinline__ float fsigmoid(float x) {
  return __builtin_amdgcn_rcpf(1.0f + __expf(-x));
}
__device__ __forceinline__ float ftanh(float x) {
  return 1.0f - 2.0f * __builtin_amdgcn_rcpf(1.0f + __expf(x + x));
}

// LDS-only barrier: order hbuf writes across waves WITHOUT draining vmcnt.
__device__ __forceinline__ void lds_barrier() {
  asm volatile("s_waitcnt lgkmcnt(0)\n\ts_barrier" ::: "memory");
}

// ---------------------------------------------------------------------------
// detect_fp32: sample x as u16; count bf16 NaN/Inf exponent patterns.
// ---------------------------------------------------------------------------
__global__ void detect_fp32(const u16* __restrict__ x, int n, int* flag) {
  __shared__ int tot;
  if (threadIdx.x == 0) tot = 0;
  __syncthreads();
  int c = 0;
  for (int i = threadIdx.x; i < n; i += blockDim.x) {
    u16 v = x[i];
    if (((v >> 7) & 0xFF) == 0xFF) ++c;
  }
  atomicAdd(&tot, c);
  __syncthreads();
  if (threadIdx.x == 0) *flag = (tot > 64) ? 1 : 0;
}

// cvt: input (fp32 or bf16 per flag) -> packed bf16 copy in ws.
__global__ void cvt(const void* __restrict__ src, u16* __restrict__ dst,
                    int n, const int* __restrict__ flag) {
  const int stride = gridDim.x * blockDim.x;
  const bool isf32 = (*flag != 0);
  for (int i = blockIdx.x * blockDim.x + threadIdx.x; i < n; i += stride) {
    if (isf32) dst[i] = f2bf(((const float*)src)[i]);
    else       dst[i] = ((const u16*)src)[i];
  }
}

// prep_bias: combined gemm bias (f32): b_ih + (n<512 ? b_hh : 0).
// b_hh for r,z gates folds into gateX; b_hn must stay separate (scaled by r).
__global__ void prep_bias(const u16* __restrict__ bih, const u16* __restrict__ bhh,
                          float* __restrict__ bc, int n) {
  int i = blockIdx.x * blockDim.x + threadIdx.x;
  if (i >= n) return;
  int col = i % G3;
  float v = bf2f(bih[i]);
  if (col < 512) v += bf2f(bhh[i]);
  bc[i] = v;
}

// write_out: fp32 staging -> d_out in the harness's output dtype per flag.
__global__ void write_out(const float* __restrict__ hNs, void* __restrict__ out,
                          int n, const int* __restrict__ flag) {
  int i = blockIdx.x * blockDim.x + threadIdx.x;
  if (i >= n) return;
  if (*flag) ((float*)out)[i] = hNs[i];
  else       ((u16*)out)[i]   = f2bf(hNs[i]);
}

// ---------------------------------------------------------------------------
// gate_gemm: C[dir][s][n][b] = sum_k A[s*64+b][k] * W[dir][n][k] + bias[dir][n]
// Output layout TRANSPOSED to [dir][S][768][64] (batch innermost) so gru_scan
// loads fragments as 8B vectors. A: [SB][K] bf16. 128x128 tile / WG, BK=64.
// ---------------------------------------------------------------------------
__global__ __launch_bounds__(256)
void gate_gemm(const u16* __restrict__ A, const u16* __restrict__ W,
               const float* __restrict__ bias, u16* __restrict__ outg, int K) {
  const int m0  = blockIdx.x * 128;
  const int n0  = blockIdx.y * 128;
  const int dir = blockIdx.z;
  W    += (size_t)dir * G3 * K;
  bias += (size_t)dir * G3;
  outg += (size_t)dir * (size_t)SB * G3;

  __shared__ __align__(16) u16 lA[8192];   // 128 rows x 64 k, chunk-swizzled
  __shared__ __align__(16) u16 lB[8192];

  const int tid  = threadIdx.x;
  const int lane = tid & 63;
  const int wv   = tid >> 6;
  const int wm   = wv & 1, wn = wv >> 1;
  const int l15  = lane & 15, quad = lane >> 4;

  floatx4 acc[4][4] = {};   // [mt][nt]

  for (int k0 = 0; k0 < K; k0 += 64) {
    bf16x8 ra[4], rb[4];
#pragma unroll
    for (int i = 0; i < 4; ++i) {
      int c   = i * 256 + tid;          // chunk 0..1023
      int row = c >> 3;
      int kc  = (c & 7) ^ (row & 7);    // XOR-swizzled source chunk
      ra[i] = *(const bf16x8*)(A + (size_t)(m0 + row) * K + (k0 + kc * 8));
      rb[i] = *(const bf16x8*)(W + (size_t)(n0 + row) * K + (k0 + kc * 8));
    }
    __syncthreads();   // previous tile's LDS reads complete
#pragma unroll
    for (int i = 0; i < 4; ++i) {
      *(bf16x8*)(lA + (size_t)(i * 256 + tid) * 8) = ra[i];
      *(bf16x8*)(lB + (size_t)(i * 256 + tid) * 8) = rb[i];
    }
    __syncthreads();

#pragma unroll
    for (int kt = 0; kt < 2; ++kt) {
      bf16x8 af[4], bfr[4];
#pragma unroll
      for (int mt = 0; mt < 4; ++mt) {
        int row = wm * 64 + mt * 16 + l15;
        int ch  = row * 8 + ((kt * 4 + quad) ^ (row & 7));
        af[mt] = *(const bf16x8*)(lA + ch * 8);
      }
#pragma unroll
      for (int nt = 0; nt < 4; ++nt) {
        int row = wn * 64 + nt * 16 + l15;
        int ch  = row * 8 + ((kt * 4 + quad) ^ (row & 7));
        bfr[nt] = *(const bf16x8*)(lB + ch * 8);
      }
#pragma unroll
      for (int mt = 0; mt < 4; ++mt)
#pragma unroll
        for (int nt = 0; nt < 4; ++nt)
          acc[mt][nt] = __builtin_amdgcn_mfma_f32_16x16x32_bf16(
              af[mt], bfr[nt], acc[mt][nt], 0, 0, 0);
    }
  }

  // epilogue: C/D layout col(n)=l15, row(m)=quad*4+r. m = m0 + wm*64 + b,
  // so s = m0/64 + wm, b = mt*16 + quad*4 + r. Pack 4 consecutive b -> 8B.
  const int sIdx = (m0 >> 6) + wm;
#pragma unroll
  for (int nt = 0; nt < 4; ++nt) {
    int n    = n0 + wn * 64 + nt * 16 + l15;
    float bv = bias[n];
#pragma unroll
    for (int mt = 0; mt < 4; ++mt) {
      bf16x4 pk;
#pragma unroll
      for (int r = 0; r < 4; ++r) pk[r] = (short)f2bf(acc[mt][nt][r] + bv);
      *(bf16x4*)(outg + ((size_t)sIdx * G3 + n) * 64 + mt * 16 + quad * 4) = pk;
    }
  }
}

// ---------------------------------------------------------------------------
// gru_scan v4: W_hh truly register-resident.
// grid = 8 WGs (dir + 2*batch_group), 1024 threads = 16 waves (4/SIMD).
// Wave wv owns hidden units [wv*16, wv*16+16): gate rows n = {j,256+j,512+j}.
// wfr = 24 bf16x8 frags = 96 VGPRs, pinned via asm so the compiler cannot
// rematerialize the loads across the per-step barrier (the v1-v3 bug:
// VGPR_Count=128 proved wfr was reloaded from global every step).
// gateX is [dir][s][768][64]: 3 x 8B fragment-layout vector loads per step.
// layerOut written cooperatively from hbuf, one step delayed, coalesced.
// ---------------------------------------------------------------------------
__global__ __launch_bounds__(1024, 4)
void gru_scan(const u16* __restrict__ gateX,   // [2][S][768][64] bf16
              const u16* __restrict__ Whh,     // [2][768][256] (this layer)
              const u16* __restrict__ Bhh,     // [2][768]
              const u16* __restrict__ H0,      // [12][64][256] bf16 copy
              u16* __restrict__ layerOut,      // [SB][512] bf16
              float* __restrict__ hNs,         // fp32 staging [12][64][256]
              int layer) {
  const int dir = blockIdx.x & 1;
  const int bg  = blockIdx.x >> 1;
  const int tid = threadIdx.x;
  const int lane = tid & 63;
  const int wv   = tid >> 6;           // 0..15: owns hidden units [wv*16, wv*16+16)
  const int l15  = lane & 15, quad = lane >> 4;

  __shared__ __align__(16) u16 hbuf[2][16][264];  // double-buffered h [batch][j]

  // stationary W_hh fragments: n = g*256 + wv*16 + l15, k = kt*32 + quad*8
  const u16* Wd = Whh + (size_t)dir * G3 * HID;
  bf16x8 wfr[8][3];                    // [kt][gate]
#pragma unroll
  for (int g = 0; g < 3; ++g) {
    int n = g * 256 + wv * 16 + l15;
#pragma unroll
    for (int kt = 0; kt < 8; ++kt)
      wfr[kt][g] = *(const bf16x8*)(Wd + (size_t)n * HID + kt * 32 + quad * 8);
  }
  // pin: make each fragment an opaque asm output -> remat across the
  // per-step barrier is illegal; values stay in VGPRs.
#pragma unroll
  for (int kt = 0; kt < 8; ++kt)
#pragma unroll
    for (int g = 0; g < 3; ++g)
      asm volatile("" : "+v"(wfr[kt][g]));

  const float bh = bf2f(Bhh[dir * G3 + 512 + wv * 16 + l15]);  // b_hn only

  const int jcol = wv * 16 + l15;      // this thread's hidden unit
  const int mrow = quad * 4;           // first of this lane's 4 batch rows
  const int b0   = bg * 16 + mrow;     // global batch row at r=0

  // init hbuf[0] cooperatively: 16 rows x 256 cols, 8B per thread
  {
    const u16* hp = H0 + ((size_t)(layer * 2 + dir) * NB + bg * 16 + wv) * HID + lane * 4;
    *(bf16x4*)(&hbuf[0][wv][lane * 4]) = *(const bf16x4*)hp;
  }
  // per-lane previous-h registers (match hbuf content exactly)
  float hreg[4];
#pragma unroll
  for (int r = 0; r < 4; ++r)
    hreg[r] = bf2f(H0[((size_t)(layer * 2 + dir) * NB + b0 + r) * HID + jcol]);

  // per-gate gateX pointers (fragment layout), advanced +/- one s per step
  const long sdelta = dir ? -(long)(G3 * 64) : (long)(G3 * 64);
  const u16 *xp0, *xp1, *xp2;
  {
    const int s0 = dir ? (S_LEN - 1) : 0;
    size_t base = (size_t)dir * SB * G3 +
                  ((size_t)s0 * G3 + jcol) * 64 + bg * 16 + quad * 4;
    xp0 = gateX + base;
    xp1 = gateX + base + 256 * 64;
    xp2 = gateX + base + 512 * 64;
  }
  bf16x4 xpre0 = *(const bf16x4*)xp0;
  bf16x4 xpre1 = *(const bf16x4*)xp1;
  bf16x4 xpre2 = *(const bf16x4*)xp2;
  xp0 += sdelta; xp1 += sdelta; xp2 += sdelta;

  lds_barrier();

  for (int t = 0; t < S_LEN; ++t) {
    const int cur = t & 1, nxt = cur ^ 1;

    // consume xpre: r/z bias already folded into gateX; x_n kept separate
    floatx4 acc0, acc1, acc2;
    bf16x4 xn = xpre2;
#pragma unroll
    for (int r = 0; r < 4; ++r) {
      acc0[r] = bf2f((u16)xpre0[r]);
      acc1[r] = bf2f((u16)xpre1[r]);
      acc2[r] = bh;
    }

    // issue next step's prefetch; stays in flight across the lds_barrier
    xpre0 = *(const bf16x4*)xp0;
    xpre1 = *(const bf16x4*)xp1;
    xpre2 = *(const bf16x4*)xp2;
    xp0 += sdelta; xp1 += sdelta; xp2 += sdelta;

    // one-step-delayed cooperative layerOut store (h(t-1) from hbuf[cur])
    if (t > 0) {
      const int sPrev = dir ? (S_LEN - t) : (t - 1);
      bf16x4 hv = *(const bf16x4*)(&hbuf[cur][wv][lane * 4]);
      *(bf16x4*)(layerOut + ((size_t)sPrev * NB + bg * 16 + wv) * 512 +
                 dir * HID + lane * 4) = hv;   // fire-and-forget
    }

    // MFMA phase: acc += h @ Whh^T   (A-frag identical for all waves)
#pragma unroll
    for (int kt = 0; kt < 8; ++kt) {
      bf16x8 af = *(const bf16x8*)(&hbuf[cur][l15][kt * 32 + quad * 8]);
      acc0 = __builtin_amdgcn_mfma_f32_16x16x32_bf16(af, wfr[kt][0], acc0, 0, 0, 0);
      acc1 = __builtin_amdgcn_mfma_f32_16x16x32_bf16(af, wfr[kt][1], acc1, 0, 0, 0);
      acc2 = __builtin_amdgcn_mfma_f32_16x16x32_bf16(af, wfr[kt][2], acc2, 0, 0, 0);
    }

    // gate phase: directly on accumulator fragments
#pragma unroll
    for (int r = 0; r < 4; ++r) {
      float rg = fsigmoid(acc0[r]);
      float zg = fsigmoid(acc1[r]);
      float ng = ftanh(bf2f((u16)xn[r]) + rg * acc2[r]);
      float hn = ng + zg * (hreg[r] - ng);
      hreg[r] = hn;
      hbuf[nxt][mrow + r][jcol] = f2bf(hn);
    }

    lds_barrier();   // h[nxt] visible; vmcnt traffic stays in flight
  }

  // final layerOut store: h(S_LEN-1) lives in hbuf[S_LEN & 1] == hbuf[0]
  {
    const int sLast = dir ? 0 : (S_LEN - 1);
    bf16x4 hv = *(const bf16x4*)(&hbuf[0][wv][lane * 4]);
    *(bf16x4*)(layerOut + ((size_t)sLast * NB + bg * 16 + wv) * 512 +
               dir * HID + lane * 4) = hv;
  }
  // epilogue: final hidden state (fp32 staging)
#pragma unroll
  for (int r = 0; r < 4; ++r)
    hNs[((size_t)(layer * 2 + dir) * NB + b0 + r) * HID + jcol] = hreg[r];
}

// ---------------------------------------------------------------------------
extern "C" void kernel_launch(void* const* d_in, const int* in_sizes, int n_in,
                              void* d_out, int out_size, void* d_ws, size_t ws_size,
                              hipStream_t stream) {
  (void)n_in; (void)ws_size;
  char* ws = (char*)d_ws;
  // ws layout (176 MiB total):
  //   [0, 4K)        flag
  //   [4K, ~772K)    hNs fp32 staging (786432 B)
  //   [~772K, ~808K) biasC f32 combined gemm bias [6][2][768]
  //   [1M, 16M)      bf16 copies: h0, wih0, wih, whh, bih, bhh (~12.8 MiB)
  //   [16M, 112M)    gateX bf16 [2][S][768][64]
  //   [112M, 144M)   bufA bf16 [SB][512]
  //   [144M, 176M)   bufB bf16 [SB][512]  (xC aliases: consumed layer 0 only)
  int*   flag  = (int*)ws;
  float* hNs   = (float*)(ws + 4096);
  float* biasC = (float*)(ws + 790528);
  u16*   h0C   = (u16*)(ws + (1u << 20));
  u16*   wih0C = h0C   + 196608;
  u16*   wihC  = wih0C + 196608;
  u16*   whhC  = wihC  + 3932160;
  u16*   bihC  = whhC  + 2359296;
  u16*   bhhC  = bihC  + 9216;
  u16*   gateX = (u16*)(ws + (16u  << 20));
  u16*   bufA  = (u16*)(ws + (112u << 20));
  u16*   bufB  = (u16*)(ws + (144u << 20));
  u16*   xC    = bufB;   // aliased; layer-0 gemm reads it before bufB written

  detect_fp32<<<1, 1024, 0, stream>>>((const u16*)d_in[0], 262144, flag);
  cvt<<<512, 256, 0, stream>>>(d_in[0], xC,    in_sizes[0], flag);
  cvt<<<256, 256, 0, stream>>>(d_in[1], h0C,   in_sizes[1], flag);
  cvt<<<256, 256, 0, stream>>>(d_in[2], wih0C, in_sizes[2], flag);
  cvt<<<512, 256, 0, stream>>>(d_in[3], wihC,  in_sizes[3], flag);
  cvt<<<512, 256, 0, stream>>>(d_in[4], whhC,  in_sizes[4], flag);
  cvt<<< 64, 256, 0, stream>>>(d_in[5], bihC,  in_sizes[5], flag);
  cvt<<< 64, 256, 0, stream>>>(d_in[6], bhhC,  in_sizes[6], flag);
  prep_bias<<<36, 256, 0, stream>>>(bihC, bhhC, biasC, NLAYER * 2 * G3);

  for (int layer = 0; layer < NLAYER; ++layer) {
    const u16* inp = (layer == 0) ? xC : ((layer & 1) ? bufA : bufB);
    u16* outBuf    = (layer & 1) ? bufB : bufA;

    const int K = (layer == 0) ? 128 : 512;
    const u16* W = (layer == 0) ? wih0C
                                : (wihC + (size_t)(layer - 1) * 2 * G3 * 512);
    dim3 grid(256, 6, 2);
    gate_gemm<<<grid, 256, 0, stream>>>(inp, W, biasC + (size_t)layer * 2 * G3,
                                        gateX, K);
    gru_scan<<<8, 1024, 0, stream>>>(gateX, whhC + (size_t)layer * 2 * G3 * HID,
                                     bhhC + (size_t)layer * 2 * G3, h0C,
                                     outBuf, hNs, layer);
  }
  write_out<<<(out_size + 255) / 256, 256, 0, stream>>>(hNs, d_out, out_size, flag);
}

// Round 4
// 6189.179 us; speedup vs baseline: 1.6107x; 1.4660x over previous
//
#include <hip/hip_runtime.h>
#include <stdint.h>

#define S_LEN 512
#define NB    64
#define HID   256
#define G3    768
#define SB    32768   // S_LEN * NB
#define NLAYER 6

typedef short bf16x8 __attribute__((ext_vector_type(8)));
typedef short bf16x4 __attribute__((ext_vector_type(4)));
typedef float floatx4 __attribute__((ext_vector_type(4)));
typedef unsigned short u16;
typedef unsigned int   u32;

__device__ __forceinline__ float bf2f(u16 v) {
  u32 u = ((u32)v) << 16;
  return __builtin_bit_cast(float, u);
}
__device__ __forceinline__ u16 f2bf(float f) {
  u32 u = __builtin_bit_cast(u32, f);
  u = (u + 0x7FFFu + ((u >> 16) & 1u)) >> 16;
  return (u16)u;
}
__device__ __forceinline__ float fsigmoid(float x) {
  return __builtin_amdgcn_rcpf(1.0f + __expf(-x));
}
__device__ __forceinline__ float ftanh(float x) {
  return 1.0f - 2.0f * __builtin_amdgcn_rcpf(1.0f + __expf(x + x));
}

// LDS-only barrier: order LDS writes across waves WITHOUT draining vmcnt.
__device__ __forceinline__ void lds_barrier() {
  asm volatile("s_waitcnt lgkmcnt(0)\n\ts_barrier" ::: "memory");
}

// ---------------------------------------------------------------------------
// detect_fp32: sample x as u16; count bf16 NaN/Inf exponent patterns.
// ---------------------------------------------------------------------------
__global__ void detect_fp32(const u16* __restrict__ x, int n, int* flag) {
  __shared__ int tot;
  if (threadIdx.x == 0) tot = 0;
  __syncthreads();
  int c = 0;
  for (int i = threadIdx.x; i < n; i += blockDim.x) {
    u16 v = x[i];
    if (((v >> 7) & 0xFF) == 0xFF) ++c;
  }
  atomicAdd(&tot, c);
  __syncthreads();
  if (threadIdx.x == 0) *flag = (tot > 64) ? 1 : 0;
}

// cvt: input (fp32 or bf16 per flag) -> packed bf16 copy in ws.
__global__ void cvt(const void* __restrict__ src, u16* __restrict__ dst,
                    int n, const int* __restrict__ flag) {
  const int stride = gridDim.x * blockDim.x;
  const bool isf32 = (*flag != 0);
  for (int i = blockIdx.x * blockDim.x + threadIdx.x; i < n; i += stride) {
    if (isf32) dst[i] = f2bf(((const float*)src)[i]);
    else       dst[i] = ((const u16*)src)[i];
  }
}

// prep_bias: combined gemm bias (f32): b_ih + (n<512 ? b_hh : 0).
__global__ void prep_bias(const u16* __restrict__ bih, const u16* __restrict__ bhh,
                          float* __restrict__ bc, int n) {
  int i = blockIdx.x * blockDim.x + threadIdx.x;
  if (i >= n) return;
  int col = i % G3;
  float v = bf2f(bih[i]);
  if (col < 512) v += bf2f(bhh[i]);
  bc[i] = v;
}

// write_out: fp32 staging -> d_out in the harness's output dtype per flag.
__global__ void write_out(const float* __restrict__ hNs, void* __restrict__ out,
                          int n, const int* __restrict__ flag) {
  int i = blockIdx.x * blockDim.x + threadIdx.x;
  if (i >= n) return;
  if (*flag) ((float*)out)[i] = hNs[i];
  else       ((u16*)out)[i]   = f2bf(hNs[i]);
}

// ---------------------------------------------------------------------------
// gate_gemm: gates = A @ W^T + bias, written in scan-native layout:
//   gateX[dir][bg(4)][s(512)][jcol(256)][gate(3)][b_in(16)]  (u16)
// so the scan's per-step loads are 6 x 8B off ONE pointer (imm offsets) and
// each WG's batch slice is line-contiguous (no cross-WG overfetch).
// A: [SB][K] bf16. 128x128 tile / WG, BK=64, XOR-swizzled LDS.
// ---------------------------------------------------------------------------
__global__ __launch_bounds__(256)
void gate_gemm(const u16* __restrict__ A, const u16* __restrict__ W,
               const float* __restrict__ bias, u16* __restrict__ outg, int K) {
  const int m0  = blockIdx.x * 128;
  const int n0  = blockIdx.y * 128;
  const int dir = blockIdx.z;
  W    += (size_t)dir * G3 * K;
  bias += (size_t)dir * G3;
  outg += (size_t)dir * (size_t)SB * G3;

  __shared__ __align__(16) u16 lA[8192];   // 128 rows x 64 k, chunk-swizzled
  __shared__ __align__(16) u16 lB[8192];

  const int tid  = threadIdx.x;
  const int lane = tid & 63;
  const int wv   = tid >> 6;
  const int wm   = wv & 1, wn = wv >> 1;
  const int l15  = lane & 15, quad = lane >> 4;

  floatx4 acc[4][4] = {};   // [mt][nt]

  for (int k0 = 0; k0 < K; k0 += 64) {
    bf16x8 ra[4], rb[4];
#pragma unroll
    for (int i = 0; i < 4; ++i) {
      int c   = i * 256 + tid;          // chunk 0..1023
      int row = c >> 3;
      int kc  = (c & 7) ^ (row & 7);    // XOR-swizzled source chunk
      ra[i] = *(const bf16x8*)(A + (size_t)(m0 + row) * K + (k0 + kc * 8));
      rb[i] = *(const bf16x8*)(W + (size_t)(n0 + row) * K + (k0 + kc * 8));
    }
    __syncthreads();   // previous tile's LDS reads complete
#pragma unroll
    for (int i = 0; i < 4; ++i) {
      *(bf16x8*)(lA + (size_t)(i * 256 + tid) * 8) = ra[i];
      *(bf16x8*)(lB + (size_t)(i * 256 + tid) * 8) = rb[i];
    }
    __syncthreads();

#pragma unroll
    for (int kt = 0; kt < 2; ++kt) {
      bf16x8 af[4], bfr[4];
#pragma unroll
      for (int mt = 0; mt < 4; ++mt) {
        int row = wm * 64 + mt * 16 + l15;
        int ch  = row * 8 + ((kt * 4 + quad) ^ (row & 7));
        af[mt] = *(const bf16x8*)(lA + ch * 8);
      }
#pragma unroll
      for (int nt = 0; nt < 4; ++nt) {
        int row = wn * 64 + nt * 16 + l15;
        int ch  = row * 8 + ((kt * 4 + quad) ^ (row & 7));
        bfr[nt] = *(const bf16x8*)(lB + ch * 8);
      }
#pragma unroll
      for (int mt = 0; mt < 4; ++mt)
#pragma unroll
        for (int nt = 0; nt < 4; ++nt)
          acc[mt][nt] = __builtin_amdgcn_mfma_f32_16x16x32_bf16(
              af[mt], bfr[nt], acc[mt][nt], 0, 0, 0);
    }
  }

  // epilogue: C/D col(n)=l15, row(m)=quad*4+r. m = s*64 + b_global where
  // s = m0/64 + wm, b_global = mt*16 + quad*4 + r -> bg = mt, b_in = quad*4+r.
  const int sIdx = (m0 >> 6) + wm;
#pragma unroll
  for (int nt = 0; nt < 4; ++nt) {
    int n    = n0 + wn * 64 + nt * 16 + l15;
    int g    = n >> 8, jc = n & 255;
    float bv = bias[n];
#pragma unroll
    for (int mt = 0; mt < 4; ++mt) {
      bf16x4 pk;
#pragma unroll
      for (int r = 0; r < 4; ++r) pk[r] = (short)f2bf(acc[mt][nt][r] + bv);
      *(bf16x4*)(outg + ((((size_t)mt * 512 + sIdx) * 256 + jc) * 3 + g) * 16 +
                 quad * 4) = pk;
    }
  }
}

// ---------------------------------------------------------------------------
// gru_scan v5: per-step W_hh traffic eliminated (the v1-v4 wall: 393 KB/WG/step
// rematerialized from L2 ~= 3000-6000 cy/step, proven by VGPR_Count<=128).
//   - 512 threads (8 waves, 2/SIMD) + amdgpu_waves_per_eu(2,2): 256-VGPR
//     budget the compiler may actually use (LDS already caps us at 1 WG/CU).
//   - r,z weights: 32 bf16x8 frags = 128 VGPRs/thread, register-resident.
//   - n-gate weights: 131 KB in LDS, loaded once, XOR slot-swizzle.
//   - h double-buffered in LDS, same swizzle. One LDS-only barrier per step.
//   - gateX in scan-native layout: 6 x 8B loads, one pointer, imm offsets.
// Wave wv owns hidden units [wv*32, wv*32+32) (2 tiles of 16).
// ---------------------------------------------------------------------------
__global__ __launch_bounds__(512)
__attribute__((amdgpu_waves_per_eu(2, 2)))
void gru_scan(const u16* __restrict__ gateX,   // [2][4][512][256][3][16] bf16
              const u16* __restrict__ Whh,     // [2][768][256] (this layer)
              const u16* __restrict__ Bhh,     // [2][768]
              const u16* __restrict__ H0,      // [12][64][256] bf16 copy
              u16* __restrict__ layerOut,      // [SB][512] bf16
              float* __restrict__ hNs,         // fp32 staging [12][64][256]
              int layer) {
  const int dir = blockIdx.x & 1;
  const int bg  = blockIdx.x >> 1;
  const int tid = threadIdx.x;
  const int lane = tid & 63;
  const int wv   = tid >> 6;           // 0..7: owns hidden units [wv*32, wv*32+32)
  const int l15  = lane & 15, quad = lane >> 4;

  // 131072 B W_hn + 16384 B h double-buffer = 147456 B (fits 160 KB/CU)
  __shared__ __align__(16) u16 wnL[65536];     // [n(256)][k(256)] slot-swizzled
  __shared__ __align__(16) u16 hb2[2][4096];   // [b(16)][j(256)] slot-swizzled

  const u16* Wd = Whh + (size_t)dir * G3 * HID;

  // --- prologue: W_hn -> LDS (once), XOR slot-swizzle (slot ^= n&7) ---
#pragma unroll
  for (int i = 0; i < 16; ++i) {
    int c    = i * 512 + tid;    // 8192 chunks of 16B
    int n    = c >> 5;
    int slot = c & 31;
    bf16x8 v = *(const bf16x8*)(Wd + (size_t)(512 + n) * HID + slot * 8);
    *(bf16x8*)(wnL + n * 256 + ((slot ^ (n & 7)) * 8)) = v;
  }

  // --- stationary r,z W fragments: 32 frags = 128 VGPRs ---
  bf16x8 wrz[8][2][2];   // [kt][gate 0=r 1=z][nt]
#pragma unroll
  for (int g = 0; g < 2; ++g)
#pragma unroll
    for (int nt = 0; nt < 2; ++nt) {
      int n = g * 256 + wv * 32 + nt * 16 + l15;
#pragma unroll
      for (int kt = 0; kt < 8; ++kt)
        wrz[kt][g][nt] = *(const bf16x8*)(Wd + (size_t)n * HID + kt * 32 + quad * 8);
    }
#pragma unroll
  for (int kt = 0; kt < 8; ++kt)
#pragma unroll
    for (int g = 0; g < 2; ++g)
#pragma unroll
      for (int nt = 0; nt < 2; ++nt)
        asm volatile("" : "+v"(wrz[kt][g][nt]));

  float bhn[2];
#pragma unroll
  for (int nt = 0; nt < 2; ++nt)
    bhn[nt] = bf2f(Bhh[dir * G3 + 512 + wv * 32 + nt * 16 + l15]);

  const int mrow = quad * 4;           // first of this lane's 4 batch rows
  const int b0   = bg * 16 + mrow;     // global batch row at r=0

  // --- init h: LDS (swizzled) + per-lane f32 registers ---
  {
    int row = tid >> 5, slot = tid & 31;
    const u16* hp = H0 + ((size_t)(layer * 2 + dir) * NB + bg * 16 + row) * HID + slot * 8;
    *(bf16x8*)(&hb2[0][row * 256 + ((slot ^ (row & 7)) * 8)]) = *(const bf16x8*)hp;
  }
  float hreg[2][4];
#pragma unroll
  for (int nt = 0; nt < 2; ++nt)
#pragma unroll
    for (int r = 0; r < 4; ++r)
      hreg[nt][r] = bf2f(H0[((size_t)(layer * 2 + dir) * NB + b0 + r) * HID +
                            wv * 32 + nt * 16 + l15]);

  // --- gateX pointer: one base, imm offsets {0,32,64} B x nt (+1536 B) ---
  const long sstep = dir ? -(long)(256 * 3 * 16) : (long)(256 * 3 * 16);
  const u16* xb;
  {
    const int s0 = dir ? (S_LEN - 1) : 0;
    xb = gateX + (size_t)dir * SB * G3 +
         ((((size_t)bg * 512 + s0) * 256 + (wv * 32 + l15)) * 3) * 16 + quad * 4;
  }
  bf16x4 xp[3][2];
#pragma unroll
  for (int g = 0; g < 3; ++g)
#pragma unroll
    for (int nt = 0; nt < 2; ++nt)
      xp[g][nt] = *(const bf16x4*)(xb + nt * 768 + g * 16);
  xb += sstep;

  lds_barrier();   // W_hn + h visible to all waves

  for (int t = 0; t < S_LEN; ++t) {
    const int cur = t & 1, nxt = cur ^ 1;

    // consume xpre (r/z have full bias folded by gemm; x_n separate)
    floatx4 aR[2], aZ[2], aN[2];
    float xnf[2][4];
#pragma unroll
    for (int nt = 0; nt < 2; ++nt)
#pragma unroll
      for (int r = 0; r < 4; ++r) {
        aR[nt][r]  = bf2f((u16)xp[0][nt][r]);
        aZ[nt][r]  = bf2f((u16)xp[1][nt][r]);
        xnf[nt][r] = bf2f((u16)xp[2][nt][r]);
        aN[nt][r]  = bhn[nt];
      }

    // next step's prefetch; stays in flight across the lds_barrier
#pragma unroll
    for (int g = 0; g < 3; ++g)
#pragma unroll
      for (int nt = 0; nt < 2; ++nt)
        xp[g][nt] = *(const bf16x4*)(xb + nt * 768 + g * 16);
    xb += sstep;

    // one-step-delayed cooperative layerOut store (reads hb2[cur])
    if (t > 0) {
      const int sPrev = dir ? (S_LEN - t) : (t - 1);
      int row = tid >> 5, slot = tid & 31;
      bf16x8 hv = *(const bf16x8*)(&hb2[cur][row * 256 + ((slot ^ (row & 7)) * 8)]);
      *(bf16x8*)(layerOut + ((size_t)sPrev * NB + bg * 16 + row) * 512 +
                 dir * HID + slot * 8) = hv;   // fire-and-forget
    }

    // MFMA phase: r,z from registers; n-gate B-frags from LDS
#pragma unroll
    for (int kt = 0; kt < 8; ++kt) {
      const int sl = ((kt * 4 + quad) ^ (l15 & 7)) * 8;
      bf16x8 af  = *(const bf16x8*)(&hb2[cur][l15 * 256 + sl]);
      bf16x8 bn0 = *(const bf16x8*)(wnL + (wv * 32 + l15) * 256 + sl);
      bf16x8 bn1 = *(const bf16x8*)(wnL + (wv * 32 + 16 + l15) * 256 + sl);
      aR[0] = __builtin_amdgcn_mfma_f32_16x16x32_bf16(af, wrz[kt][0][0], aR[0], 0, 0, 0);
      aR[1] = __builtin_amdgcn_mfma_f32_16x16x32_bf16(af, wrz[kt][0][1], aR[1], 0, 0, 0);
      aZ[0] = __builtin_amdgcn_mfma_f32_16x16x32_bf16(af, wrz[kt][1][0], aZ[0], 0, 0, 0);
      aZ[1] = __builtin_amdgcn_mfma_f32_16x16x32_bf16(af, wrz[kt][1][1], aZ[1], 0, 0, 0);
      aN[0] = __builtin_amdgcn_mfma_f32_16x16x32_bf16(af, bn0,           aN[0], 0, 0, 0);
      aN[1] = __builtin_amdgcn_mfma_f32_16x16x32_bf16(af, bn1,           aN[1], 0, 0, 0);
    }

    // gate phase: directly on accumulator fragments
#pragma unroll
    for (int nt = 0; nt < 2; ++nt) {
      const int jc  = wv * 32 + nt * 16 + l15;
      const int jhi = jc >> 3, jlo = jc & 7;
#pragma unroll
      for (int r = 0; r < 4; ++r) {
        float rg = fsigmoid(aR[nt][r]);
        float zg = fsigmoid(aZ[nt][r]);
        float ng = ftanh(xnf[nt][r] + rg * aN[nt][r]);
        float hn = ng + zg * (hreg[nt][r] - ng);
        hreg[nt][r] = hn;
        int b = mrow + r;
        hb2[nxt][b * 256 + ((jhi ^ (b & 7)) * 8) + jlo] = f2bf(hn);
      }
    }

    lds_barrier();   // h[nxt] visible; vmcnt traffic stays in flight
  }

  // final layerOut store: h(last) is in hb2[0] (t=511: nxt=0)
  {
    const int sLast = dir ? 0 : (S_LEN - 1);
    int row = tid >> 5, slot = tid & 31;
    bf16x8 hv = *(const bf16x8*)(&hb2[0][row * 256 + ((slot ^ (row & 7)) * 8)]);
    *(bf16x8*)(layerOut + ((size_t)sLast * NB + bg * 16 + row) * 512 +
               dir * HID + slot * 8) = hv;
  }
  // epilogue: final hidden state (fp32 staging)
#pragma unroll
  for (int nt = 0; nt < 2; ++nt)
#pragma unroll
    for (int r = 0; r < 4; ++r)
      hNs[((size_t)(layer * 2 + dir) * NB + b0 + r) * HID +
          wv * 32 + nt * 16 + l15] = hreg[nt][r];
}

// ---------------------------------------------------------------------------
extern "C" void kernel_launch(void* const* d_in, const int* in_sizes, int n_in,
                              void* d_out, int out_size, void* d_ws, size_t ws_size,
                              hipStream_t stream) {
  (void)n_in; (void)ws_size;
  char* ws = (char*)d_ws;
  int*   flag  = (int*)ws;
  float* hNs   = (float*)(ws + 4096);
  float* biasC = (float*)(ws + 790528);
  u16*   h0C   = (u16*)(ws + (1u << 20));
  u16*   wih0C = h0C   + 196608;
  u16*   wihC  = wih0C + 196608;
  u16*   whhC  = wihC  + 3932160;
  u16*   bihC  = whhC  + 2359296;
  u16*   bhhC  = bihC  + 9216;
  u16*   gateX = (u16*)(ws + (16u  << 20));
  u16*   bufA  = (u16*)(ws + (112u << 20));
  u16*   bufB  = (u16*)(ws + (144u << 20));
  u16*   xC    = bufB;   // aliased; layer-0 gemm reads it before bufB written

  detect_fp32<<<1, 1024, 0, stream>>>((const u16*)d_in[0], 262144, flag);
  cvt<<<512, 256, 0, stream>>>(d_in[0], xC,    in_sizes[0], flag);
  cvt<<<256, 256, 0, stream>>>(d_in[1], h0C,   in_sizes[1], flag);
  cvt<<<256, 256, 0, stream>>>(d_in[2], wih0C, in_sizes[2], flag);
  cvt<<<512, 256, 0, stream>>>(d_in[3], wihC,  in_sizes[3], flag);
  cvt<<<512, 256, 0, stream>>>(d_in[4], whhC,  in_sizes[4], flag);
  cvt<<< 64, 256, 0, stream>>>(d_in[5], bihC,  in_sizes[5], flag);
  cvt<<< 64, 256, 0, stream>>>(d_in[6], bhhC,  in_sizes[6], flag);
  prep_bias<<<36, 256, 0, stream>>>(bihC, bhhC, biasC, NLAYER * 2 * G3);

  for (int layer = 0; layer < NLAYER; ++layer) {
    const u16* inp = (layer == 0) ? xC : ((layer & 1) ? bufA : bufB);
    u16* outBuf    = (layer & 1) ? bufB : bufA;

    const int K = (layer == 0) ? 128 : 512;
    const u16* W = (layer == 0) ? wih0C
                                : (wihC + (size_t)(layer - 1) * 2 * G3 * 512);
    dim3 grid(256, 6, 2);
    gate_gemm<<<grid, 256, 0, stream>>>(inp, W, biasC + (size_t)layer * 2 * G3,
                                        gateX, K);
    gru_scan<<<8, 512, 0, stream>>>(gateX, whhC + (size_t)layer * 2 * G3 * HID,
                                    bhhC + (size_t)layer * 2 * G3, h0C,
                                    outBuf, hNs, layer);
  }
  write_out<<<(out_size + 255) / 256, 256, 0, stream>>>(hNs, d_out, out_size, flag);
}